// Round 12
// baseline (414.784 us; speedup 1.0000x reference)
//
#include <hip/hip_runtime.h>
#include <stdint.h>

typedef short bf16x8 __attribute__((ext_vector_type(8)));
typedef float f32x4 __attribute__((ext_vector_type(4)));
typedef unsigned short u16x8 __attribute__((ext_vector_type(8)));

__device__ __forceinline__ unsigned short f2bf(float f){
  uint32_t u = __builtin_bit_cast(uint32_t, f);
  u += 0x7FFFu + ((u >> 16) & 1u);
  return (unsigned short)(u >> 16);
}
__device__ __forceinline__ float bf2f(unsigned short h){
  uint32_t u = ((uint32_t)h) << 16;
  return __builtin_bit_cast(float, u);
}
__device__ __forceinline__ float bflo(uint32_t dw){
  return __builtin_bit_cast(float, dw << 16);
}
__device__ __forceinline__ float bfhi(uint32_t dw){
  return __builtin_bit_cast(float, dw & 0xffff0000u);
}

__device__ __forceinline__ void gload_lds16(const void* g, void* l){
  __builtin_amdgcn_global_load_lds(
      (const __attribute__((address_space(1))) uint32_t*)(g),
      (__attribute__((address_space(3))) uint32_t*)(l),
      16, 0, 0);
}

// ---------------- convert x (fp32 -> bf16), 8 elems/thread ----------------
__global__ __launch_bounds__(256) void convert_x_k(const float* __restrict__ x,
                                                   unsigned short* __restrict__ xb){
  size_t i = (size_t)blockIdx.x * 256 + threadIdx.x;
  const float4* p = (const float4*)x + i * 2;
  float4 a = p[0], b = p[1];
  u16x8 o;
  o[0] = f2bf(a.x); o[1] = f2bf(a.y); o[2] = f2bf(a.z); o[3] = f2bf(a.w);
  o[4] = f2bf(b.x); o[5] = f2bf(b.y); o[6] = f2bf(b.z); o[7] = f2bf(b.w);
  *(u16x8*)(xb + i * 8) = o;
}

// ------------- tiled transpose + convert weights (coalesced both sides) ----
__global__ __launch_bounds__(256) void transpose_w_k(const float* __restrict__ Wqkv,
                                                     const float* __restrict__ Wproj,
                                                     unsigned short* __restrict__ Wqkvt,
                                                     unsigned short* __restrict__ Wprojt){
  __shared__ unsigned short t[64][68];
  int bid = blockIdx.x;
  const float* src; unsigned short* dst; int c0, j0, sstride, dstride;
  if (bid < 192){
    src = Wqkv;  dst = Wqkvt;  sstride = 1536; dstride = 512;
    c0 = (bid / 24) * 64;  j0 = (bid % 24) * 64;
  } else {
    int e = bid - 192;
    src = Wproj; dst = Wprojt; sstride = 512;  dstride = 512;
    c0 = (e >> 3) * 64;    j0 = (e & 7) * 64;
  }
  int tid = threadIdx.x;
  int rl = tid >> 6;
  int cl = tid & 63;
  #pragma unroll
  for (int i = 0; i < 16; ++i){
    int cr = i * 4 + rl;
    t[cl][cr] = f2bf(src[(size_t)(c0 + cr) * sstride + j0 + cl]);
  }
  __syncthreads();
  #pragma unroll
  for (int i = 0; i < 16; ++i){
    int jr = i * 4 + rl;
    dst[(size_t)(j0 + jr) * dstride + c0 + cl] = t[jr][cl];
  }
}

// ------ gemm_qkv: 256x256 tile, single-buffer 64KB LDS, 2-barrier loop -----
// 8 waves as 2M x 4N (wave owns 128x64): 12 ds_read_b128 per kk serve 32
// MFMA (0.375 reads/MFMA vs 0.5 at 64x64 waves) — attacks the LDS-issue
// bound. 2 blocks/CU by LDS. Conflict-free XOR chunk swizzle throughout.
__global__ __launch_bounds__(512, 2) void gemm_qkv(
    const unsigned short* __restrict__ A,
    const unsigned short* __restrict__ Bt,
    const float* __restrict__ bias,
    const float* __restrict__ pos_enc,
    unsigned short* __restrict__ oq,
    unsigned short* __restrict__ ok,
    unsigned short* __restrict__ ov,
    int NTN)
{
  __shared__ unsigned short As[256 * 64];
  __shared__ unsigned short Bs[256 * 64];
  int tid = threadIdx.x, lane = tid & 63, wid = tid >> 6;
  int nwg = gridDim.x;
  int b0 = blockIdx.x;
  int cpx = nwg >> 3;
  int swz = (b0 & 7) * cpx + (b0 >> 3);      // XCD swizzle (nwg % 8 == 0)
  int tm = swz / NTN, tn = swz - tm * NTN;
  int row0 = tm << 8, col0 = tn << 8;
  int wrow = wid >> 2, wcol = wid & 3;       // wave owns 128x64 of C

  f32x4 acc[8][4];
  #pragma unroll
  for (int m = 0; m < 8; ++m)
    #pragma unroll
    for (int n = 0; n < 4; ++n)
      acc[m][n] = (f32x4){0.f, 0.f, 0.f, 0.f};

  for (int kt = 0; kt < 8; ++kt){
    int k0 = kt * 64;
    #pragma unroll
    for (int it = 0; it < 4; ++it){          // A: 2048 chunks of 16B
      int c = it * 512 + tid;
      int r = c >> 3;
      int scs = ((c & 7) ^ (r & 7)) * 8;     // swizzled source k-col (elems)
      gload_lds16(A + (size_t)(row0 + r) * 512 + k0 + scs, &As[c * 8]);
    }
    #pragma unroll
    for (int it = 0; it < 4; ++it){          // B: 2048 chunks of 16B
      int c = it * 512 + tid;
      int r = c >> 3;
      int scs = ((c & 7) ^ (r & 7)) * 8;
      gload_lds16(Bt + (size_t)(col0 + r) * 512 + k0 + scs, &Bs[c * 8]);
    }
    __syncthreads();
    #pragma unroll
    for (int kk = 0; kk < 2; ++kk){
      int kcs = ((kk * 4 + (lane >> 4)) ^ (lane & 7)) * 8;   // swizzled chunk
      bf16x8 bfr[4];
      #pragma unroll
      for (int n = 0; n < 4; ++n)
        bfr[n] = *(const bf16x8*)&Bs[(wcol * 64 + n * 16 + (lane & 15)) * 64 + kcs];
      #pragma unroll
      for (int m = 0; m < 8; ++m){
        bf16x8 af = *(const bf16x8*)&As[(wrow * 128 + m * 16 + (lane & 15)) * 64 + kcs];
        #pragma unroll
        for (int n = 0; n < 4; ++n)
          acc[m][n] = __builtin_amdgcn_mfma_f32_16x16x32_bf16(af, bfr[n], acc[m][n], 0, 0, 0);
      }
    }
    __syncthreads();
  }

  // LDS-staged epilogue: wave-private 4KB bf16 scratch in As.
  int part = col0 >> 9;                    // block-uniform: q/k/v (256-tile never straddles)
  int ccb = (col0 & 511) + wcol * 64;      // part-local col base of wave
  unsigned short* scr = &As[wid * 2048];
  #pragma unroll
  for (int mh = 0; mh < 4; ++mh){          // 4 groups of 32 rows
    #pragma unroll
    for (int mm = 0; mm < 2; ++mm){
      int m = mh * 2 + mm;
      #pragma unroll
      for (int n = 0; n < 4; ++n){
        #pragma unroll
        for (int r = 0; r < 4; ++r){
          int lrow = mm * 16 + (lane >> 4) * 4 + r;     // 0..31
          int lcol = n * 16 + (lane & 15);              // 0..63
          float val = acc[m][n][r] + bias[col0 + wcol * 64 + lcol];
          if (part == 0) val = fmaxf(val, 0.f);
          int pch = (lcol >> 3) ^ ((lrow >> 2) & 3);
          scr[lrow * 64 + pch * 8 + (lcol & 7)] = f2bf(val);
        }
      }
    }
    #pragma unroll
    for (int i = 0; i < 4; ++i){
      int idx = i * 64 + lane;                          // 0..255
      int r2 = idx >> 3, c2 = idx & 7;
      int pch = c2 ^ ((r2 >> 2) & 3);
      u16x8 vals = *(const u16x8*)&scr[r2 * 64 + pch * 8];
      int grow = row0 + wrow * 128 + mh * 32 + r2;
      int bb = grow >> 12, nn = grow & 4095;
      int cc = ccb + c2 * 8;
      int h = cc >> 5, d = cc & 31;
      size_t dst = ((size_t)((bb << 4) + h) * 4096 + nn) * 32 + d;
      if (part == 1){
        const float4* pe = (const float4*)(pos_enc + (size_t)nn * 512 + cc);
        float4 p0 = pe[0], p1 = pe[1];
        u16x8 o;
        o[0] = f2bf(fmaxf(bf2f(vals[0]) + p0.x, 0.f));
        o[1] = f2bf(fmaxf(bf2f(vals[1]) + p0.y, 0.f));
        o[2] = f2bf(fmaxf(bf2f(vals[2]) + p0.z, 0.f));
        o[3] = f2bf(fmaxf(bf2f(vals[3]) + p0.w, 0.f));
        o[4] = f2bf(fmaxf(bf2f(vals[4]) + p1.x, 0.f));
        o[5] = f2bf(fmaxf(bf2f(vals[5]) + p1.y, 0.f));
        o[6] = f2bf(fmaxf(bf2f(vals[6]) + p1.z, 0.f));
        o[7] = f2bf(fmaxf(bf2f(vals[7]) + p1.w, 0.f));
        *(u16x8*)(ok + dst) = o;
      } else if (part == 0){
        *(u16x8*)(oq + dst) = vals;
      } else {
        *(u16x8*)(ov + dst) = vals;
      }
    }
  }
}

// ------ gemm_proj: 256x256, counted-vmcnt dbuf pipeline (r10 winner) ------
__global__ __launch_bounds__(512, 1) void gemm_proj(
    const unsigned short* __restrict__ A,
    const unsigned short* __restrict__ Bt,
    const float* __restrict__ bias,
    float* __restrict__ op,
    int NTN)
{
  __shared__ unsigned short As[2][256 * 64];
  __shared__ unsigned short Bs[2][256 * 64];
  int tid = threadIdx.x, lane = tid & 63, wid = tid >> 6;
  int nwg = gridDim.x;
  int b0 = blockIdx.x;
  int cpx = nwg >> 3;
  int swz = (b0 & 7) * cpx + (b0 >> 3);
  int tm = swz / NTN, tn = swz - tm * NTN;
  int row0 = tm << 8, col0 = tn << 8;
  int wrow = wid >> 2, wcol = wid & 3;       // wave owns 128x64 of C

  f32x4 acc[8][4];
  #pragma unroll
  for (int m = 0; m < 8; ++m)
    #pragma unroll
    for (int n = 0; n < 4; ++n)
      acc[m][n] = (f32x4){0.f, 0.f, 0.f, 0.f};

  auto STAGE = [&](int buf, int kt){
    int k0 = kt * 64;
    #pragma unroll
    for (int it = 0; it < 4; ++it){
      int c = it * 512 + tid;
      int r = c >> 3;
      int scs = ((c & 7) ^ (r & 7)) * 8;
      gload_lds16(A + (size_t)(row0 + r) * 512 + k0 + scs, &As[buf][c * 8]);
    }
    #pragma unroll
    for (int it = 0; it < 4; ++it){
      int c = it * 512 + tid;
      int r = c >> 3;
      int scs = ((c & 7) ^ (r & 7)) * 8;
      gload_lds16(Bt + (size_t)(col0 + r) * 512 + k0 + scs, &Bs[buf][c * 8]);
    }
  };
  auto COMPUTE = [&](int buf){
    bf16x8 bfr[4][2];
    #pragma unroll
    for (int kk = 0; kk < 2; ++kk){
      int kcs = ((kk * 4 + (lane >> 4)) ^ (lane & 7)) * 8;
      #pragma unroll
      for (int n = 0; n < 4; ++n)
        bfr[n][kk] = *(const bf16x8*)&Bs[buf][(wcol * 64 + n * 16 + (lane & 15)) * 64 + kcs];
    }
    __builtin_amdgcn_s_setprio(1);
    #pragma unroll
    for (int kk = 0; kk < 2; ++kk){
      int kcs = ((kk * 4 + (lane >> 4)) ^ (lane & 7)) * 8;
      #pragma unroll
      for (int m = 0; m < 8; ++m){
        bf16x8 af = *(const bf16x8*)&As[buf][(wrow * 128 + m * 16 + (lane & 15)) * 64 + kcs];
        #pragma unroll
        for (int n = 0; n < 4; ++n)
          acc[m][n] = __builtin_amdgcn_mfma_f32_16x16x32_bf16(af, bfr[n][kk], acc[m][n], 0, 0, 0);
      }
    }
    __builtin_amdgcn_s_setprio(0);
  };

  STAGE(0, 0);
  STAGE(1, 1);
  #pragma unroll
  for (int t = 0; t < 8; ++t){
    if (t < 7) asm volatile("s_waitcnt vmcnt(8)" ::: "memory");
    else       asm volatile("s_waitcnt vmcnt(0)" ::: "memory");
    __builtin_amdgcn_s_barrier();
    __builtin_amdgcn_sched_barrier(0);
    COMPUTE(t & 1);
    asm volatile("" ::: "memory");
    __builtin_amdgcn_s_barrier();
    if (t + 2 < 8) STAGE(t & 1, t + 2);
  }

  #pragma unroll
  for (int m = 0; m < 8; ++m){
    #pragma unroll
    for (int n = 0; n < 4; ++n){
      #pragma unroll
      for (int r = 0; r < 4; ++r){
        int rrow = row0 + wrow * 128 + m * 16 + (lane >> 4) * 4 + r;
        int ccol = col0 + wcol * 64 + n * 16 + (lane & 15);
        op[(size_t)rrow * 512 + ccol] = acc[m][n][r] + bias[ccol];
      }
    }
  }
}

// ---- kv = k^T v (32x32) + ksum + emit pair-planar v_p (fused transpose) ---
__global__ __launch_bounds__(256) void kv_k(const unsigned short* __restrict__ kbuf,
                                            const unsigned short* __restrict__ vbuf,
                                            float* __restrict__ kvb,
                                            float* __restrict__ ksb,
                                            uint32_t* __restrict__ vp){
  int bh  = blockIdx.x >> 2;
  int seg = blockIdx.x & 3;
  __shared__ float ks[64][36];
  __shared__ float vs[64][36];
  __shared__ float red[4][64][16];
  __shared__ float ksred[4][8][4];
  int tid = threadIdx.x;
  int g = tid >> 6, gi = tid & 63;
  int c0 = (gi >> 3) * 4, d0 = (gi & 7) * 4;
  float acc[4][4] = {};
  float ksacc[4] = {0.f, 0.f, 0.f, 0.f};
  const unsigned short* kb = kbuf + (size_t)bh * 4096 * 32 + (size_t)seg * 1024 * 32;
  const unsigned short* vb = vbuf + (size_t)bh * 4096 * 32 + (size_t)seg * 1024 * 32;
  uint32_t* vpb = vp + (size_t)bh * 65536 + seg * 1024;
  int er = tid >> 2;
  int ec = (tid & 3) * 8;
  for (int t = 0; t < 16; ++t){
    __syncthreads();
    u16x8 kk8 = *(const u16x8*)(kb + ((size_t)t * 64 + er) * 32 + ec);
    u16x8 vv8 = *(const u16x8*)(vb + ((size_t)t * 64 + er) * 32 + ec);
    #pragma unroll
    for (int i = 0; i < 8; ++i){ ks[er][ec + i] = bf2f(kk8[i]); vs[er][ec + i] = bf2f(vv8[i]); }
    __syncthreads();
    #pragma unroll
    for (int i = 0; i < 4; ++i){
      int idx = i * 256 + tid;
      int pr = idx >> 6, tok = idx & 63;
      uint32_t pk = ((uint32_t)f2bf(vs[tok][pr * 2 + 1]) << 16)
                  |  (uint32_t)f2bf(vs[tok][pr * 2]);
      vpb[pr * 4096 + t * 64 + tok] = pk;
    }
    for (int nn = g; nn < 64; nn += 4){
      f32x4 k4 = *(const f32x4*)&ks[nn][c0];
      f32x4 v4 = *(const f32x4*)&vs[nn][d0];
      #pragma unroll
      for (int i = 0; i < 4; ++i)
        #pragma unroll
        for (int j = 0; j < 4; ++j)
          acc[i][j] += k4[i] * v4[j];
      if ((gi & 7) == 0){
        #pragma unroll
        for (int i = 0; i < 4; ++i) ksacc[i] += k4[i];
      }
    }
  }
  __syncthreads();
  #pragma unroll
  for (int i = 0; i < 4; ++i)
    #pragma unroll
    for (int j = 0; j < 4; ++j)
      red[g][gi][i * 4 + j] = acc[i][j];
  if ((gi & 7) == 0){
    #pragma unroll
    for (int i = 0; i < 4; ++i) ksred[g][gi >> 3][i] = ksacc[i];
  }
  __syncthreads();
  for (int s = tid; s < 1024; s += 256){
    int gi2 = s >> 4, e = s & 15;
    float sum = red[0][gi2][e] + red[1][gi2][e] + red[2][gi2][e] + red[3][gi2][e];
    int c = (gi2 >> 3) * 4 + (e >> 2), d = (gi2 & 7) * 4 + (e & 3);
    atomicAdd(&kvb[bh * 1024 + c * 32 + d], sum);
  }
  if (tid < 32){
    float s = ksred[0][tid >> 2][tid & 3] + ksred[1][tid >> 2][tid & 3]
            + ksred[2][tid >> 2][tid & 3] + ksred[3][tid >> 2][tid & 3];
    atomicAdd(&ksb[bh * 32 + tid], s);
  }
}

// ------- out = z*(q@kv) + depthwise5x5(v_p) + bias, coalesced I/O ----------
__global__ __launch_bounds__(256, 2) void attn_k3(
    const unsigned short* __restrict__ qbuf,
    const uint32_t* __restrict__ vp,
    const float* __restrict__ kvb,
    const float* __restrict__ ksb,
    const float* __restrict__ dwc_w,
    const float* __restrict__ dwc_b,
    unsigned short* __restrict__ attn)
{
  int band = blockIdx.x;
  int bh   = blockIdx.y;
  int tid = threadIdx.x, lane = tid & 63, w = tid >> 6;
  __shared__ uint32_t outs32[1024][18];
  unsigned short* outs = (unsigned short*)outs32;
  __shared__ float zs[1024];
  __shared__ float ksum_s[32];

  const unsigned short* qb = qbuf + (size_t)bh * 4096 * 32 + (size_t)band * 1024 * 32;
  const uint32_t* vpb = vp + (size_t)bh * 65536;

  if (tid < 32) ksum_s[tid] = ksb[bh * 32 + tid];
  __syncthreads();

  for (int p = 0; p < 4; ++p){
    int t = p * 256 + tid;
    float zd = 0.f;
    #pragma unroll
    for (int pp = 0; pp < 4; ++pp){
      u16x8 qq = *(const u16x8*)(qb + (size_t)t * 32 + pp * 8);
      #pragma unroll
      for (int i = 0; i < 8; ++i) zd += bf2f(qq[i]) * ksum_s[pp * 8 + i];
    }
    zs[t] = 1.f / (zd + 1e-6f);
  }

  bf16x8 bfr[2];
  #pragma unroll
  for (int nc = 0; nc < 2; ++nc){
    bf16x8 t8;
    #pragma unroll
    for (int j = 0; j < 8; ++j){
      int c = (lane >> 4) * 8 + j;
      int d = nc * 16 + (lane & 15);
      t8[j] = (short)f2bf(kvb[bh * 1024 + c * 32 + d]);
    }
    bfr[nc] = t8;
  }
  __syncthreads();

  for (int p = 0; p < 4; ++p){
    f32x4 acc[4][2];
    #pragma unroll
    for (int m = 0; m < 4; ++m){ acc[m][0] = (f32x4){0.f,0.f,0.f,0.f}; acc[m][1] = (f32x4){0.f,0.f,0.f,0.f}; }
    #pragma unroll
    for (int m = 0; m < 4; ++m){
      int row = p * 256 + w * 64 + m * 16 + (lane & 15);
      bf16x8 af = *(const bf16x8*)(qb + (size_t)row * 32 + (lane >> 4) * 8);
      acc[m][0] = __builtin_amdgcn_mfma_f32_16x16x32_bf16(af, bfr[0], acc[m][0], 0, 0, 0);
      acc[m][1] = __builtin_amdgcn_mfma_f32_16x16x32_bf16(af, bfr[1], acc[m][1], 0, 0, 0);
    }
    #pragma unroll
    for (int m = 0; m < 4; ++m)
      #pragma unroll
      for (int nc = 0; nc < 2; ++nc)
        #pragma unroll
        for (int r = 0; r < 4; ++r){
          int lrow = p * 256 + w * 64 + m * 16 + (lane >> 4) * 4 + r;
          int col = nc * 16 + (lane & 15);
          outs[lrow * 36 + col] = f2bf(acc[m][nc][r] * zs[lrow]);
        }
  }
  __syncthreads();

  int x = lane;
  int y0 = band * 16;
  int xm2 = lane - 2, xm1 = lane - 1, xp1 = lane + 1, xp2 = lane + 2;

  for (int pair = 0; pair < 4; ++pair){
    int dbase = w * 8 + pair * 2;
    int pr = w * 4 + pair;
    float w0[25], w1[25];
    #pragma unroll
    for (int j = 0; j < 25; ++j){
      w0[j] = dwc_w[dbase * 25 + j];
      w1[j] = dwc_w[(dbase + 1) * 25 + j];
    }
    float cb0 = dwc_b[dbase], cb1 = dwc_b[dbase + 1];

    uint32_t rowd[20];
    #pragma unroll
    for (int il = 0; il < 20; ++il){
      int yi = y0 - 2 + il;
      rowd[il] = (yi >= 0 && yi < 64)
        ? vpb[pr * 4096 + yi * 64 + x] : 0u;
    }

    float a0[5], a1[5];
    #pragma unroll
    for (int il = 0; il < 20; ++il){
      uint32_t d0 = rowd[il];
      uint32_t dm2 = (uint32_t)__shfl((int)d0, xm2); if (lane < 2)  dm2 = 0;
      uint32_t dm1 = (uint32_t)__shfl((int)d0, xm1); if (lane < 1)  dm1 = 0;
      uint32_t dp1 = (uint32_t)__shfl((int)d0, xp1); if (lane > 62) dp1 = 0;
      uint32_t dp2 = (uint32_t)__shfl((int)d0, xp2); if (lane > 61) dp2 = 0;
      float f0[5], f1[5];
      f0[0] = bflo(dm2); f1[0] = bfhi(dm2);
      f0[1] = bflo(dm1); f1[1] = bfhi(dm1);
      f0[2] = bflo(d0);  f1[2] = bfhi(d0);
      f0[3] = bflo(dp1); f1[3] = bfhi(dp1);
      f0[4] = bflo(dp2); f1[4] = bfhi(dp2);
      #pragma unroll
      for (int ky = 0; ky < 5; ++ky){
        int ol = il - ky;
        if (ol < 0 || ol > 15) continue;
        int s = ol % 5;
        if (ky == 0){
          a0[s] = w0[0] * f0[0];
          a1[s] = w1[0] * f1[0];
          #pragma unroll
          for (int kx = 1; kx < 5; ++kx){
            a0[s] += w0[kx] * f0[kx];
            a1[s] += w1[kx] * f1[kx];
          }
        } else {
          #pragma unroll
          for (int kx = 0; kx < 5; ++kx){
            a0[s] += w0[ky * 5 + kx] * f0[kx];
            a1[s] += w1[ky * 5 + kx] * f1[kx];
          }
        }
      }
      if (il >= 4){
        int ol = il - 4;
        int s = ol % 5;
        int ltok = ol * 64 + x;
        uint32_t ov = outs32[ltok][pr];
        float o0 = bflo(ov) + a0[s] + cb0;
        float o1 = bfhi(ov) + a1[s] + cb1;
        outs32[ltok][pr] = ((uint32_t)f2bf(o1) << 16) | (uint32_t)f2bf(o0);
      }
    }
  }
  __syncthreads();

  int b = bh >> 4, h = bh & 15;
  size_t gbase = ((size_t)b * 4096 + (size_t)band * 1024) * 512 + h * 32;
  #pragma unroll
  for (int it = 0; it < 32; ++it){
    int idx = it * 256 + tid;
    int token = idx >> 3, sub = idx & 7;
    uint2 vv = *(const uint2*)&outs32[token][sub * 2];
    *(uint2*)(attn + gbase + (size_t)token * 512 + sub * 4) = vv;
  }
}

extern "C" void kernel_launch(void* const* d_in, const int* in_sizes, int n_in,
                              void* d_out, int out_size, void* d_ws, size_t ws_size,
                              hipStream_t stream) {
  const float* x       = (const float*)d_in[0];
  const float* Wqkv    = (const float*)d_in[1];
  const float* bqkv    = (const float*)d_in[2];
  const float* pos_enc = (const float*)d_in[3];
  const float* dwc_w   = (const float*)d_in[4];
  const float* dwc_b   = (const float*)d_in[5];
  const float* Wproj   = (const float*)d_in[6];
  const float* bproj   = (const float*)d_in[7];
  float* out = (float*)d_out;
  char* ws = (char*)d_ws;

  const size_t off_xb    = 0;                 // xb; reused as v_p after gemm_qkv
  const size_t off_wqkvt = 67108864;
  const size_t off_wprojt= 68681728;
  const size_t off_q     = 69206016;
  const size_t off_k     = 136314880;
  const size_t off_v     = 203423744;
  const size_t off_kv    = 270532608;
  const size_t off_ksum  = 271581184;
  const size_t needed    = 271613952;
  if (ws_size < needed) return;

  unsigned short* xb     = (unsigned short*)(ws + off_xb);
  unsigned short* wqkvt  = (unsigned short*)(ws + off_wqkvt);
  unsigned short* wprojt = (unsigned short*)(ws + off_wprojt);
  unsigned short* qb     = (unsigned short*)(ws + off_q);
  unsigned short* kb     = (unsigned short*)(ws + off_k);
  unsigned short* vb     = (unsigned short*)(ws + off_v);
  float* kvb = (float*)(ws + off_kv);
  float* ksb = (float*)(ws + off_ksum);
  unsigned short* attn = kb;                  // k dead after kv_k
  uint32_t* vp = (uint32_t*)(ws + off_xb);    // xb dead after gemm_qkv

  convert_x_k<<<16384, 256, 0, stream>>>(x, xb);
  transpose_w_k<<<256, 256, 0, stream>>>(Wqkv, Wproj, wqkvt, wprojt);
  gemm_qkv<<<1536, 512, 0, stream>>>(xb, wqkvt, bqkv, pos_enc, qb, kb, vb, 6);
  (void)hipMemsetAsync(kvb, 0, (size_t)(256 * 1024 + 256 * 32) * sizeof(float), stream);
  kv_k<<<1024, 256, 0, stream>>>(kb, vb, kvb, ksb, vp);
  attn_k3<<<dim3(4, 256), 256, 0, stream>>>(qb, vp, kvb, ksb, dwc_w, dwc_b, attn);
  gemm_proj<<<512, 512, 0, stream>>>(attn, wprojt, bproj, out, 2);
}

// Round 13
// 366.788 us; speedup vs baseline: 1.1309x; 1.1309x over previous
//
#include <hip/hip_runtime.h>
#include <stdint.h>

typedef short bf16x8 __attribute__((ext_vector_type(8)));
typedef float f32x4 __attribute__((ext_vector_type(4)));
typedef unsigned short u16x8 __attribute__((ext_vector_type(8)));

__device__ __forceinline__ unsigned short f2bf(float f){
  uint32_t u = __builtin_bit_cast(uint32_t, f);
  u += 0x7FFFu + ((u >> 16) & 1u);
  return (unsigned short)(u >> 16);
}
__device__ __forceinline__ float bf2f(unsigned short h){
  uint32_t u = ((uint32_t)h) << 16;
  return __builtin_bit_cast(float, u);
}
__device__ __forceinline__ float bflo(uint32_t dw){
  return __builtin_bit_cast(float, dw << 16);
}
__device__ __forceinline__ float bfhi(uint32_t dw){
  return __builtin_bit_cast(float, dw & 0xffff0000u);
}

__device__ __forceinline__ void gload_lds16(const void* g, void* l){
  __builtin_amdgcn_global_load_lds(
      (const __attribute__((address_space(1))) uint32_t*)(g),
      (__attribute__((address_space(3))) uint32_t*)(l),
      16, 0, 0);
}

// ---------------- convert x (fp32 -> bf16), 8 elems/thread ----------------
__global__ __launch_bounds__(256) void convert_x_k(const float* __restrict__ x,
                                                   unsigned short* __restrict__ xb){
  size_t i = (size_t)blockIdx.x * 256 + threadIdx.x;
  const float4* p = (const float4*)x + i * 2;
  float4 a = p[0], b = p[1];
  u16x8 o;
  o[0] = f2bf(a.x); o[1] = f2bf(a.y); o[2] = f2bf(a.z); o[3] = f2bf(a.w);
  o[4] = f2bf(b.x); o[5] = f2bf(b.y); o[6] = f2bf(b.z); o[7] = f2bf(b.w);
  *(u16x8*)(xb + i * 8) = o;
}

// ------------- tiled transpose + convert weights (coalesced both sides) ----
__global__ __launch_bounds__(256) void transpose_w_k(const float* __restrict__ Wqkv,
                                                     const float* __restrict__ Wproj,
                                                     unsigned short* __restrict__ Wqkvt,
                                                     unsigned short* __restrict__ Wprojt){
  __shared__ unsigned short t[64][68];
  int bid = blockIdx.x;
  const float* src; unsigned short* dst; int c0, j0, sstride, dstride;
  if (bid < 192){
    src = Wqkv;  dst = Wqkvt;  sstride = 1536; dstride = 512;
    c0 = (bid / 24) * 64;  j0 = (bid % 24) * 64;
  } else {
    int e = bid - 192;
    src = Wproj; dst = Wprojt; sstride = 512;  dstride = 512;
    c0 = (e >> 3) * 64;    j0 = (e & 7) * 64;
  }
  int tid = threadIdx.x;
  int rl = tid >> 6;
  int cl = tid & 63;
  #pragma unroll
  for (int i = 0; i < 16; ++i){
    int cr = i * 4 + rl;
    t[cl][cr] = f2bf(src[(size_t)(c0 + cr) * sstride + j0 + cl]);
  }
  __syncthreads();
  #pragma unroll
  for (int i = 0; i < 16; ++i){
    int jr = i * 4 + rl;
    dst[(size_t)(j0 + jr) * dstride + c0 + cl] = t[jr][cl];
  }
}

// ------ gemm_qkv: 256x128 tile, 8 waves, 2-barrier loop (r9/r11 winner) ----
__global__ __launch_bounds__(512, 2) void gemm_qkv(
    const unsigned short* __restrict__ A,
    const unsigned short* __restrict__ Bt,
    const float* __restrict__ bias,
    const float* __restrict__ pos_enc,
    unsigned short* __restrict__ oq,
    unsigned short* __restrict__ ok,
    unsigned short* __restrict__ ov,
    int NTN)
{
  __shared__ unsigned short As[256 * 64];
  __shared__ unsigned short Bs[128 * 64];
  int tid = threadIdx.x, lane = tid & 63, wid = tid >> 6;
  int nwg = gridDim.x;
  int b0 = blockIdx.x;
  int cpx = nwg >> 3;
  int swz = (b0 & 7) * cpx + (b0 >> 3);      // XCD swizzle (nwg % 8 == 0)
  int tm = swz / NTN, tn = swz - tm * NTN;
  int row0 = tm << 8, col0 = tn << 7;
  int wr = wid >> 1, wc = wid & 1;           // 4M x 2N waves, each owns 64x64

  f32x4 acc[4][4];
  #pragma unroll
  for (int m = 0; m < 4; ++m)
    #pragma unroll
    for (int n = 0; n < 4; ++n)
      acc[m][n] = (f32x4){0.f, 0.f, 0.f, 0.f};

  for (int kt = 0; kt < 8; ++kt){
    int k0 = kt * 64;
    #pragma unroll
    for (int it = 0; it < 4; ++it){          // A: 2048 chunks of 16B
      int c = it * 512 + tid;
      int r = c >> 3;
      int scs = ((c & 7) ^ (r & 7)) * 8;     // swizzled source k-col (elems)
      gload_lds16(A + (size_t)(row0 + r) * 512 + k0 + scs, &As[c * 8]);
    }
    #pragma unroll
    for (int it = 0; it < 2; ++it){          // B: 1024 chunks of 16B
      int c = it * 512 + tid;
      int r = c >> 3;
      int scs = ((c & 7) ^ (r & 7)) * 8;
      gload_lds16(Bt + (size_t)(col0 + r) * 512 + k0 + scs, &Bs[c * 8]);
    }
    __syncthreads();
    #pragma unroll
    for (int kk = 0; kk < 2; ++kk){
      bf16x8 af[4], bfr[4];
      int kcs = ((kk * 4 + (lane >> 4)) ^ (lane & 7)) * 8;   // swizzled chunk
      #pragma unroll
      for (int m = 0; m < 4; ++m)
        af[m] = *(const bf16x8*)&As[(wr * 64 + m * 16 + (lane & 15)) * 64 + kcs];
      #pragma unroll
      for (int n = 0; n < 4; ++n)
        bfr[n] = *(const bf16x8*)&Bs[(wc * 64 + n * 16 + (lane & 15)) * 64 + kcs];
      #pragma unroll
      for (int m = 0; m < 4; ++m)
        #pragma unroll
        for (int n = 0; n < 4; ++n)
          acc[m][n] = __builtin_amdgcn_mfma_f32_16x16x32_bf16(af[m], bfr[n], acc[m][n], 0, 0, 0);
    }
    __syncthreads();
  }

  // LDS-staged epilogue: wave-private 32x64 bf16 scratch (4KB) in As.
  int part = col0 >> 9;                    // block-uniform: q/k/v
  int ccb = (col0 & 511) + wc * 64;        // part-local col base of wave
  unsigned short* scr = &As[wid * 2048];
  #pragma unroll
  for (int mh = 0; mh < 2; ++mh){
    #pragma unroll
    for (int mm = 0; mm < 2; ++mm){
      int m = mh * 2 + mm;
      #pragma unroll
      for (int n = 0; n < 4; ++n){
        #pragma unroll
        for (int r = 0; r < 4; ++r){
          int lrow = mm * 16 + (lane >> 4) * 4 + r;     // 0..31
          int lcol = n * 16 + (lane & 15);              // 0..63
          float val = acc[m][n][r] + bias[col0 + wc * 64 + lcol];
          if (part == 0) val = fmaxf(val, 0.f);
          int pch = (lcol >> 3) ^ ((lrow >> 2) & 3);
          scr[lrow * 64 + pch * 8 + (lcol & 7)] = f2bf(val);
        }
      }
    }
    #pragma unroll
    for (int i = 0; i < 4; ++i){
      int idx = i * 64 + lane;                          // 0..255
      int r2 = idx >> 3, c2 = idx & 7;
      int pch = c2 ^ ((r2 >> 2) & 3);
      u16x8 vals = *(const u16x8*)&scr[r2 * 64 + pch * 8];
      int grow = row0 + wr * 64 + mh * 32 + r2;
      int bb = grow >> 12, nn = grow & 4095;
      int cc = ccb + c2 * 8;
      int h = cc >> 5, d = cc & 31;
      size_t dst = ((size_t)((bb << 4) + h) * 4096 + nn) * 32 + d;
      if (part == 1){
        const float4* pe = (const float4*)(pos_enc + (size_t)nn * 512 + cc);
        float4 p0 = pe[0], p1 = pe[1];
        u16x8 o;
        o[0] = f2bf(fmaxf(bf2f(vals[0]) + p0.x, 0.f));
        o[1] = f2bf(fmaxf(bf2f(vals[1]) + p0.y, 0.f));
        o[2] = f2bf(fmaxf(bf2f(vals[2]) + p0.z, 0.f));
        o[3] = f2bf(fmaxf(bf2f(vals[3]) + p0.w, 0.f));
        o[4] = f2bf(fmaxf(bf2f(vals[4]) + p1.x, 0.f));
        o[5] = f2bf(fmaxf(bf2f(vals[5]) + p1.y, 0.f));
        o[6] = f2bf(fmaxf(bf2f(vals[6]) + p1.z, 0.f));
        o[7] = f2bf(fmaxf(bf2f(vals[7]) + p1.w, 0.f));
        *(u16x8*)(ok + dst) = o;
      } else if (part == 0){
        *(u16x8*)(oq + dst) = vals;
      } else {
        *(u16x8*)(ov + dst) = vals;
      }
    }
  }
}

// ------ gemm_proj: 256x256, counted-vmcnt dbuf pipeline (r10 winner) ------
__global__ __launch_bounds__(512, 1) void gemm_proj(
    const unsigned short* __restrict__ A,
    const unsigned short* __restrict__ Bt,
    const float* __restrict__ bias,
    float* __restrict__ op,
    int NTN)
{
  __shared__ unsigned short As[2][256 * 64];
  __shared__ unsigned short Bs[2][256 * 64];
  int tid = threadIdx.x, lane = tid & 63, wid = tid >> 6;
  int nwg = gridDim.x;
  int b0 = blockIdx.x;
  int cpx = nwg >> 3;
  int swz = (b0 & 7) * cpx + (b0 >> 3);
  int tm = swz / NTN, tn = swz - tm * NTN;
  int row0 = tm << 8, col0 = tn << 8;
  int wrow = wid >> 2, wcol = wid & 3;       // wave owns 128x64 of C

  f32x4 acc[8][4];
  #pragma unroll
  for (int m = 0; m < 8; ++m)
    #pragma unroll
    for (int n = 0; n < 4; ++n)
      acc[m][n] = (f32x4){0.f, 0.f, 0.f, 0.f};

  auto STAGE = [&](int buf, int kt){
    int k0 = kt * 64;
    #pragma unroll
    for (int it = 0; it < 4; ++it){
      int c = it * 512 + tid;
      int r = c >> 3;
      int scs = ((c & 7) ^ (r & 7)) * 8;
      gload_lds16(A + (size_t)(row0 + r) * 512 + k0 + scs, &As[buf][c * 8]);
    }
    #pragma unroll
    for (int it = 0; it < 4; ++it){
      int c = it * 512 + tid;
      int r = c >> 3;
      int scs = ((c & 7) ^ (r & 7)) * 8;
      gload_lds16(Bt + (size_t)(col0 + r) * 512 + k0 + scs, &Bs[buf][c * 8]);
    }
  };
  auto COMPUTE = [&](int buf){
    bf16x8 bfr[4][2];
    #pragma unroll
    for (int kk = 0; kk < 2; ++kk){
      int kcs = ((kk * 4 + (lane >> 4)) ^ (lane & 7)) * 8;
      #pragma unroll
      for (int n = 0; n < 4; ++n)
        bfr[n][kk] = *(const bf16x8*)&Bs[buf][(wcol * 64 + n * 16 + (lane & 15)) * 64 + kcs];
    }
    __builtin_amdgcn_s_setprio(1);
    #pragma unroll
    for (int kk = 0; kk < 2; ++kk){
      int kcs = ((kk * 4 + (lane >> 4)) ^ (lane & 7)) * 8;
      #pragma unroll
      for (int m = 0; m < 8; ++m){
        bf16x8 af = *(const bf16x8*)&As[buf][(wrow * 128 + m * 16 + (lane & 15)) * 64 + kcs];
        #pragma unroll
        for (int n = 0; n < 4; ++n)
          acc[m][n] = __builtin_amdgcn_mfma_f32_16x16x32_bf16(af, bfr[n][kk], acc[m][n], 0, 0, 0);
      }
    }
    __builtin_amdgcn_s_setprio(0);
  };

  STAGE(0, 0);
  STAGE(1, 1);
  #pragma unroll
  for (int t = 0; t < 8; ++t){
    if (t < 7) asm volatile("s_waitcnt vmcnt(8)" ::: "memory");
    else       asm volatile("s_waitcnt vmcnt(0)" ::: "memory");
    __builtin_amdgcn_s_barrier();
    __builtin_amdgcn_sched_barrier(0);
    COMPUTE(t & 1);
    asm volatile("" ::: "memory");
    __builtin_amdgcn_s_barrier();
    if (t + 2 < 8) STAGE(t & 1, t + 2);
  }

  #pragma unroll
  for (int m = 0; m < 8; ++m){
    #pragma unroll
    for (int n = 0; n < 4; ++n){
      #pragma unroll
      for (int r = 0; r < 4; ++r){
        int rrow = row0 + wrow * 128 + m * 16 + (lane >> 4) * 4 + r;
        int ccol = col0 + wcol * 64 + n * 16 + (lane & 15);
        op[(size_t)rrow * 512 + ccol] = acc[m][n][r] + bias[ccol];
      }
    }
  }
}

// ---- kv = k^T v via MFMA + ksum via ones-fragment + pair-planar v_p ------
// Per (bh,seg): stage k,v TRANSPOSED in LDS as bf16 [32 ch][64 tok] with
// chunk ^= (row + row>>3)&7 swizzle; wave (t&3) MFMAs its 1/4 of K.
__global__ __launch_bounds__(256) void kv_k(const unsigned short* __restrict__ kbuf,
                                            const unsigned short* __restrict__ vbuf,
                                            float* __restrict__ kvb,
                                            float* __restrict__ ksb,
                                            uint32_t* __restrict__ vp){
  int bh  = blockIdx.x >> 2;
  int seg = blockIdx.x & 3;
  __shared__ unsigned short ksT[32 * 64];
  __shared__ unsigned short vsT[32 * 64];
  __shared__ float red[4][1024];
  __shared__ float red2[4][32];
  int tid = threadIdx.x, lane = tid & 63, w = tid >> 6;
  const unsigned short* kb = kbuf + (size_t)bh * 131072 + (size_t)seg * 32768;
  const unsigned short* vb = vbuf + (size_t)bh * 131072 + (size_t)seg * 32768;
  uint32_t* vpb = vp + (size_t)bh * 65536 + seg * 1024;

  f32x4 acc00 = (f32x4){0,0,0,0}, acc01 = (f32x4){0,0,0,0};
  f32x4 acc10 = (f32x4){0,0,0,0}, acc11 = (f32x4){0,0,0,0};
  f32x4 ksa0  = (f32x4){0,0,0,0}, ksa1  = (f32x4){0,0,0,0};
  bf16x8 ones;
  #pragma unroll
  for (int j = 0; j < 8; ++j) ones[j] = (short)0x3F80;   // bf16 1.0

  int tok = tid >> 2;        // 0..63
  int ec  = (tid & 3) * 8;   // channel base 0,8,16,24

  for (int t = 0; t < 16; ++t){
    __syncthreads();         // prior tile's reads complete
    u16x8 kk8 = *(const u16x8*)(kb + ((size_t)t * 64 + tok) * 32 + ec);
    u16x8 vv8 = *(const u16x8*)(vb + ((size_t)t * 64 + tok) * 32 + ec);
    #pragma unroll
    for (int j = 0; j < 8; ++j){
      int row = ec + j;
      int sw = (row + (row >> 3)) & 7;
      int col = ((((tok >> 3) ^ sw) << 3) | (tok & 7));
      ksT[row * 64 + col] = kk8[j];
      vsT[row * 64 + col] = vv8[j];
    }
    __syncthreads();         // tile ready
    // pair-planar v_p emit (coalesced dword stores)
    #pragma unroll
    for (int i = 0; i < 4; ++i){
      int idx = i * 256 + tid;
      int pr = idx >> 6, tk = idx & 63;
      int r0 = pr * 2, r1 = r0 + 1;
      int sw0 = (r0 + (r0 >> 3)) & 7;
      int sw1 = (r1 + (r1 >> 3)) & 7;
      uint32_t lo = ksT[0]; // dummy init avoided; real below
      lo = vsT[r0 * 64 + ((((tk >> 3) ^ sw0) << 3) | (tk & 7))];
      uint32_t hi = vsT[r1 * 64 + ((((tk >> 3) ^ sw1) << 3) | (tk & 7))];
      vpb[pr * 4096 + t * 64 + tk] = lo | (hi << 16);
    }
    if ((t & 3) == w){       // this wave owns this K-slice
      #pragma unroll
      for (int kk = 0; kk < 2; ++kk){
        int kc = kk * 4 + (lane >> 4);       // 16B chunk of k-offset
        int r0 = lane & 15, r1 = 16 + (lane & 15);
        int sw0 = (r0 + (r0 >> 3)) & 7;
        int sw1 = (r1 + (r1 >> 3)) & 7;
        bf16x8 a0 = *(const bf16x8*)&ksT[r0 * 64 + ((kc ^ sw0) << 3)];
        bf16x8 a1 = *(const bf16x8*)&ksT[r1 * 64 + ((kc ^ sw1) << 3)];
        bf16x8 b0 = *(const bf16x8*)&vsT[r0 * 64 + ((kc ^ sw0) << 3)];
        bf16x8 b1 = *(const bf16x8*)&vsT[r1 * 64 + ((kc ^ sw1) << 3)];
        acc00 = __builtin_amdgcn_mfma_f32_16x16x32_bf16(a0, b0, acc00, 0, 0, 0);
        acc01 = __builtin_amdgcn_mfma_f32_16x16x32_bf16(a0, b1, acc01, 0, 0, 0);
        acc10 = __builtin_amdgcn_mfma_f32_16x16x32_bf16(a1, b0, acc10, 0, 0, 0);
        acc11 = __builtin_amdgcn_mfma_f32_16x16x32_bf16(a1, b1, acc11, 0, 0, 0);
        ksa0  = __builtin_amdgcn_mfma_f32_16x16x32_bf16(a0, ones, ksa0, 0, 0, 0);
        ksa1  = __builtin_amdgcn_mfma_f32_16x16x32_bf16(a1, ones, ksa1, 0, 0, 0);
      }
    }
  }
  __syncthreads();
  {
    int q = lane >> 4, c16 = lane & 15;
    #pragma unroll
    for (int r = 0; r < 4; ++r){
      red[w][(q * 4 + r) * 32 + c16]           = acc00[r];
      red[w][(q * 4 + r) * 32 + 16 + c16]      = acc01[r];
      red[w][(16 + q * 4 + r) * 32 + c16]      = acc10[r];
      red[w][(16 + q * 4 + r) * 32 + 16 + c16] = acc11[r];
    }
    if (c16 == 0){
      #pragma unroll
      for (int r = 0; r < 4; ++r){
        red2[w][q * 4 + r]      = ksa0[r];
        red2[w][16 + q * 4 + r] = ksa1[r];
      }
    }
  }
  __syncthreads();
  for (int s = tid; s < 1024; s += 256){
    float sum = red[0][s] + red[1][s] + red[2][s] + red[3][s];
    atomicAdd(&kvb[bh * 1024 + s], sum);
  }
  if (tid < 32){
    atomicAdd(&ksb[bh * 32 + tid],
              red2[0][tid] + red2[1][tid] + red2[2][tid] + red2[3][tid]);
  }
}

// ------- out = z*(q@kv) + depthwise5x5(v_p) + bias, coalesced I/O ----------
__global__ __launch_bounds__(256, 2) void attn_k3(
    const unsigned short* __restrict__ qbuf,
    const uint32_t* __restrict__ vp,
    const float* __restrict__ kvb,
    const float* __restrict__ ksb,
    const float* __restrict__ dwc_w,
    const float* __restrict__ dwc_b,
    unsigned short* __restrict__ attn)
{
  int band = blockIdx.x;
  int bh   = blockIdx.y;
  int tid = threadIdx.x, lane = tid & 63, w = tid >> 6;
  __shared__ uint32_t outs32[1024][18];
  unsigned short* outs = (unsigned short*)outs32;
  __shared__ float zs[1024];
  __shared__ float ksum_s[32];

  const unsigned short* qb = qbuf + (size_t)bh * 4096 * 32 + (size_t)band * 1024 * 32;
  const uint32_t* vpb = vp + (size_t)bh * 65536;

  if (tid < 32) ksum_s[tid] = ksb[bh * 32 + tid];
  __syncthreads();

  for (int p = 0; p < 4; ++p){
    int t = p * 256 + tid;
    float zd = 0.f;
    #pragma unroll
    for (int pp = 0; pp < 4; ++pp){
      u16x8 qq = *(const u16x8*)(qb + (size_t)t * 32 + pp * 8);
      #pragma unroll
      for (int i = 0; i < 8; ++i) zd += bf2f(qq[i]) * ksum_s[pp * 8 + i];
    }
    zs[t] = 1.f / (zd + 1e-6f);
  }

  bf16x8 bfr[2];
  #pragma unroll
  for (int nc = 0; nc < 2; ++nc){
    bf16x8 t8;
    #pragma unroll
    for (int j = 0; j < 8; ++j){
      int c = (lane >> 4) * 8 + j;
      int d = nc * 16 + (lane & 15);
      t8[j] = (short)f2bf(kvb[bh * 1024 + c * 32 + d]);
    }
    bfr[nc] = t8;
  }
  __syncthreads();

  for (int p = 0; p < 4; ++p){
    f32x4 acc[4][2];
    #pragma unroll
    for (int m = 0; m < 4; ++m){ acc[m][0] = (f32x4){0.f,0.f,0.f,0.f}; acc[m][1] = (f32x4){0.f,0.f,0.f,0.f}; }
    #pragma unroll
    for (int m = 0; m < 4; ++m){
      int row = p * 256 + w * 64 + m * 16 + (lane & 15);
      bf16x8 af = *(const bf16x8*)(qb + (size_t)row * 32 + (lane >> 4) * 8);
      acc[m][0] = __builtin_amdgcn_mfma_f32_16x16x32_bf16(af, bfr[0], acc[m][0], 0, 0, 0);
      acc[m][1] = __builtin_amdgcn_mfma_f32_16x16x32_bf16(af, bfr[1], acc[m][1], 0, 0, 0);
    }
    #pragma unroll
    for (int m = 0; m < 4; ++m)
      #pragma unroll
      for (int nc = 0; nc < 2; ++nc)
        #pragma unroll
        for (int r = 0; r < 4; ++r){
          int lrow = p * 256 + w * 64 + m * 16 + (lane >> 4) * 4 + r;
          int col = nc * 16 + (lane & 15);
          outs[lrow * 36 + col] = f2bf(acc[m][nc][r] * zs[lrow]);
        }
  }
  __syncthreads();

  int x = lane;
  int y0 = band * 16;
  int xm2 = lane - 2, xm1 = lane - 1, xp1 = lane + 1, xp2 = lane + 2;

  for (int pair = 0; pair < 4; ++pair){
    int dbase = w * 8 + pair * 2;
    int pr = w * 4 + pair;
    float w0[25], w1[25];
    #pragma unroll
    for (int j = 0; j < 25; ++j){
      w0[j] = dwc_w[dbase * 25 + j];
      w1[j] = dwc_w[(dbase + 1) * 25 + j];
    }
    float cb0 = dwc_b[dbase], cb1 = dwc_b[dbase + 1];

    uint32_t rowd[20];
    #pragma unroll
    for (int il = 0; il < 20; ++il){
      int yi = y0 - 2 + il;
      rowd[il] = (yi >= 0 && yi < 64)
        ? vpb[pr * 4096 + yi * 64 + x] : 0u;
    }

    float a0[5], a1[5];
    #pragma unroll
    for (int il = 0; il < 20; ++il){
      uint32_t d0 = rowd[il];
      uint32_t dm2 = (uint32_t)__shfl((int)d0, xm2); if (lane < 2)  dm2 = 0;
      uint32_t dm1 = (uint32_t)__shfl((int)d0, xm1); if (lane < 1)  dm1 = 0;
      uint32_t dp1 = (uint32_t)__shfl((int)d0, xp1); if (lane > 62) dp1 = 0;
      uint32_t dp2 = (uint32_t)__shfl((int)d0, xp2); if (lane > 61) dp2 = 0;
      float f0[5], f1[5];
      f0[0] = bflo(dm2); f1[0] = bfhi(dm2);
      f0[1] = bflo(dm1); f1[1] = bfhi(dm1);
      f0[2] = bflo(d0);  f1[2] = bfhi(d0);
      f0[3] = bflo(dp1); f1[3] = bfhi(dp1);
      f0[4] = bflo(dp2); f1[4] = bfhi(dp2);
      #pragma unroll
      for (int ky = 0; ky < 5; ++ky){
        int ol = il - ky;
        if (ol < 0 || ol > 15) continue;
        int s = ol % 5;
        if (ky == 0){
          a0[s] = w0[0] * f0[0];
          a1[s] = w1[0] * f1[0];
          #pragma unroll
          for (int kx = 1; kx < 5; ++kx){
            a0[s] += w0[kx] * f0[kx];
            a1[s] += w1[kx] * f1[kx];
          }
        } else {
          #pragma unroll
          for (int kx = 0; kx < 5; ++kx){
            a0[s] += w0[ky * 5 + kx] * f0[kx];
            a1[s] += w1[ky * 5 + kx] * f1[kx];
          }
        }
      }
      if (il >= 4){
        int ol = il - 4;
        int s = ol % 5;
        int ltok = ol * 64 + x;
        uint32_t ov = outs32[ltok][pr];
        float o0 = bflo(ov) + a0[s] + cb0;
        float o1 = bfhi(ov) + a1[s] + cb1;
        outs32[ltok][pr] = ((uint32_t)f2bf(o1) << 16) | (uint32_t)f2bf(o0);
      }
    }
  }
  __syncthreads();

  int b = bh >> 4, h = bh & 15;
  size_t gbase = ((size_t)b * 4096 + (size_t)band * 1024) * 512 + h * 32;
  #pragma unroll
  for (int it = 0; it < 32; ++it){
    int idx = it * 256 + tid;
    int token = idx >> 3, sub = idx & 7;
    uint2 vv = *(const uint2*)&outs32[token][sub * 2];
    *(uint2*)(attn + gbase + (size_t)token * 512 + sub * 4) = vv;
  }
}

extern "C" void kernel_launch(void* const* d_in, const int* in_sizes, int n_in,
                              void* d_out, int out_size, void* d_ws, size_t ws_size,
                              hipStream_t stream) {
  const float* x       = (const float*)d_in[0];
  const float* Wqkv    = (const float*)d_in[1];
  const float* bqkv    = (const float*)d_in[2];
  const float* pos_enc = (const float*)d_in[3];
  const float* dwc_w   = (const float*)d_in[4];
  const float* dwc_b   = (const float*)d_in[5];
  const float* Wproj   = (const float*)d_in[6];
  const float* bproj   = (const float*)d_in[7];
  float* out = (float*)d_out;
  char* ws = (char*)d_ws;

  const size_t off_xb    = 0;                 // xb; reused as v_p after gemm_qkv
  const size_t off_wqkvt = 67108864;
  const size_t off_wprojt= 68681728;
  const size_t off_q     = 69206016;
  const size_t off_k     = 136314880;
  const size_t off_v     = 203423744;
  const size_t off_kv    = 270532608;
  const size_t off_ksum  = 271581184;
  const size_t needed    = 271613952;
  if (ws_size < needed) return;

  unsigned short* xb     = (unsigned short*)(ws + off_xb);
  unsigned short* wqkvt  = (unsigned short*)(ws + off_wqkvt);
  unsigned short* wprojt = (unsigned short*)(ws + off_wprojt);
  unsigned short* qb     = (unsigned short*)(ws + off_q);
  unsigned short* kb     = (unsigned short*)(ws + off_k);
  unsigned short* vb     = (unsigned short*)(ws + off_v);
  float* kvb = (float*)(ws + off_kv);
  float* ksb = (float*)(ws + off_ksum);
  unsigned short* attn = kb;                  // k dead after kv_k
  uint32_t* vp = (uint32_t*)(ws + off_xb);    // xb dead after gemm_qkv

  convert_x_k<<<16384, 256, 0, stream>>>(x, xb);
  transpose_w_k<<<256, 256, 0, stream>>>(Wqkv, Wproj, wqkvt, wprojt);
  gemm_qkv<<<3072, 512, 0, stream>>>(xb, wqkvt, bqkv, pos_enc, qb, kb, vb, 12);
  (void)hipMemsetAsync(kvb, 0, (size_t)(256 * 1024 + 256 * 32) * sizeof(float), stream);
  kv_k<<<1024, 256, 0, stream>>>(kb, vb, kvb, ksb, vp);
  attn_k3<<<dim3(4, 256), 256, 0, stream>>>(qb, vp, kvb, ksb, dwc_w, dwc_b, attn);
  gemm_proj<<<512, 512, 0, stream>>>(attn, wprojt, bproj, out, 2);
}

// Round 14
// 363.750 us; speedup vs baseline: 1.1403x; 1.0084x over previous
//
#include <hip/hip_runtime.h>
#include <stdint.h>

typedef short bf16x8 __attribute__((ext_vector_type(8)));
typedef float f32x4 __attribute__((ext_vector_type(4)));
typedef unsigned short u16x8 __attribute__((ext_vector_type(8)));

__device__ __forceinline__ unsigned short f2bf(float f){
  uint32_t u = __builtin_bit_cast(uint32_t, f);
  u += 0x7FFFu + ((u >> 16) & 1u);
  return (unsigned short)(u >> 16);
}
__device__ __forceinline__ float bf2f(unsigned short h){
  uint32_t u = ((uint32_t)h) << 16;
  return __builtin_bit_cast(float, u);
}
__device__ __forceinline__ float bflo(uint32_t dw){
  return __builtin_bit_cast(float, dw << 16);
}
__device__ __forceinline__ float bfhi(uint32_t dw){
  return __builtin_bit_cast(float, dw & 0xffff0000u);
}

__device__ __forceinline__ void gload_lds16(const void* g, void* l){
  __builtin_amdgcn_global_load_lds(
      (const __attribute__((address_space(1))) uint32_t*)(g),
      (__attribute__((address_space(3))) uint32_t*)(l),
      16, 0, 0);
}

// ---------------- convert x (fp32 -> bf16), 8 elems/thread ----------------
__global__ __launch_bounds__(256) void convert_x_k(const float* __restrict__ x,
                                                   unsigned short* __restrict__ xb){
  size_t i = (size_t)blockIdx.x * 256 + threadIdx.x;
  const float4* p = (const float4*)x + i * 2;
  float4 a = p[0], b = p[1];
  u16x8 o;
  o[0] = f2bf(a.x); o[1] = f2bf(a.y); o[2] = f2bf(a.z); o[3] = f2bf(a.w);
  o[4] = f2bf(b.x); o[5] = f2bf(b.y); o[6] = f2bf(b.z); o[7] = f2bf(b.w);
  *(u16x8*)(xb + i * 8) = o;
}

// ------------- tiled transpose + convert weights (coalesced both sides) ----
__global__ __launch_bounds__(256) void transpose_w_k(const float* __restrict__ Wqkv,
                                                     const float* __restrict__ Wproj,
                                                     unsigned short* __restrict__ Wqkvt,
                                                     unsigned short* __restrict__ Wprojt){
  __shared__ unsigned short t[64][68];
  int bid = blockIdx.x;
  const float* src; unsigned short* dst; int c0, j0, sstride, dstride;
  if (bid < 192){
    src = Wqkv;  dst = Wqkvt;  sstride = 1536; dstride = 512;
    c0 = (bid / 24) * 64;  j0 = (bid % 24) * 64;
  } else {
    int e = bid - 192;
    src = Wproj; dst = Wprojt; sstride = 512;  dstride = 512;
    c0 = (e >> 3) * 64;    j0 = (e & 7) * 64;
  }
  int tid = threadIdx.x;
  int rl = tid >> 6;
  int cl = tid & 63;
  #pragma unroll
  for (int i = 0; i < 16; ++i){
    int cr = i * 4 + rl;
    t[cl][cr] = f2bf(src[(size_t)(c0 + cr) * sstride + j0 + cl]);
  }
  __syncthreads();
  #pragma unroll
  for (int i = 0; i < 16; ++i){
    int jr = i * 4 + rl;
    dst[(size_t)(j0 + jr) * dstride + c0 + cl] = t[jr][cl];
  }
}

// ------ gemm_qkv: 256x128 tile, 8 waves, 2-barrier loop (r9/r11 winner) ----
__global__ __launch_bounds__(512, 2) void gemm_qkv(
    const unsigned short* __restrict__ A,
    const unsigned short* __restrict__ Bt,
    const float* __restrict__ bias,
    const float* __restrict__ pos_enc,
    unsigned short* __restrict__ oq,
    unsigned short* __restrict__ ok,
    unsigned short* __restrict__ ov,
    int NTN)
{
  __shared__ unsigned short As[256 * 64];
  __shared__ unsigned short Bs[128 * 64];
  int tid = threadIdx.x, lane = tid & 63, wid = tid >> 6;
  int nwg = gridDim.x;
  int b0 = blockIdx.x;
  int cpx = nwg >> 3;
  int swz = (b0 & 7) * cpx + (b0 >> 3);      // XCD swizzle (nwg % 8 == 0)
  int tm = swz / NTN, tn = swz - tm * NTN;
  int row0 = tm << 8, col0 = tn << 7;
  int wr = wid >> 1, wc = wid & 1;           // 4M x 2N waves, each owns 64x64

  f32x4 acc[4][4];
  #pragma unroll
  for (int m = 0; m < 4; ++m)
    #pragma unroll
    for (int n = 0; n < 4; ++n)
      acc[m][n] = (f32x4){0.f, 0.f, 0.f, 0.f};

  for (int kt = 0; kt < 8; ++kt){
    int k0 = kt * 64;
    #pragma unroll
    for (int it = 0; it < 4; ++it){          // A: 2048 chunks of 16B
      int c = it * 512 + tid;
      int r = c >> 3;
      int scs = ((c & 7) ^ (r & 7)) * 8;     // swizzled source k-col (elems)
      gload_lds16(A + (size_t)(row0 + r) * 512 + k0 + scs, &As[c * 8]);
    }
    #pragma unroll
    for (int it = 0; it < 2; ++it){          // B: 1024 chunks of 16B
      int c = it * 512 + tid;
      int r = c >> 3;
      int scs = ((c & 7) ^ (r & 7)) * 8;
      gload_lds16(Bt + (size_t)(col0 + r) * 512 + k0 + scs, &Bs[c * 8]);
    }
    __syncthreads();
    #pragma unroll
    for (int kk = 0; kk < 2; ++kk){
      bf16x8 af[4], bfr[4];
      int kcs = ((kk * 4 + (lane >> 4)) ^ (lane & 7)) * 8;   // swizzled chunk
      #pragma unroll
      for (int m = 0; m < 4; ++m)
        af[m] = *(const bf16x8*)&As[(wr * 64 + m * 16 + (lane & 15)) * 64 + kcs];
      #pragma unroll
      for (int n = 0; n < 4; ++n)
        bfr[n] = *(const bf16x8*)&Bs[(wc * 64 + n * 16 + (lane & 15)) * 64 + kcs];
      #pragma unroll
      for (int m = 0; m < 4; ++m)
        #pragma unroll
        for (int n = 0; n < 4; ++n)
          acc[m][n] = __builtin_amdgcn_mfma_f32_16x16x32_bf16(af[m], bfr[n], acc[m][n], 0, 0, 0);
    }
    __syncthreads();
  }

  // LDS-staged epilogue: wave-private 32x64 bf16 scratch (4KB) in As.
  int part = col0 >> 9;                    // block-uniform: q/k/v
  int ccb = (col0 & 511) + wc * 64;        // part-local col base of wave
  unsigned short* scr = &As[wid * 2048];
  #pragma unroll
  for (int mh = 0; mh < 2; ++mh){
    #pragma unroll
    for (int mm = 0; mm < 2; ++mm){
      int m = mh * 2 + mm;
      #pragma unroll
      for (int n = 0; n < 4; ++n){
        #pragma unroll
        for (int r = 0; r < 4; ++r){
          int lrow = mm * 16 + (lane >> 4) * 4 + r;     // 0..31
          int lcol = n * 16 + (lane & 15);              // 0..63
          float val = acc[m][n][r] + bias[col0 + wc * 64 + lcol];
          if (part == 0) val = fmaxf(val, 0.f);
          int pch = (lcol >> 3) ^ ((lrow >> 2) & 3);
          scr[lrow * 64 + pch * 8 + (lcol & 7)] = f2bf(val);
        }
      }
    }
    #pragma unroll
    for (int i = 0; i < 4; ++i){
      int idx = i * 64 + lane;                          // 0..255
      int r2 = idx >> 3, c2 = idx & 7;
      int pch = c2 ^ ((r2 >> 2) & 3);
      u16x8 vals = *(const u16x8*)&scr[r2 * 64 + pch * 8];
      int grow = row0 + wr * 64 + mh * 32 + r2;
      int bb = grow >> 12, nn = grow & 4095;
      int cc = ccb + c2 * 8;
      int h = cc >> 5, d = cc & 31;
      size_t dst = ((size_t)((bb << 4) + h) * 4096 + nn) * 32 + d;
      if (part == 1){
        const float4* pe = (const float4*)(pos_enc + (size_t)nn * 512 + cc);
        float4 p0 = pe[0], p1 = pe[1];
        u16x8 o;
        o[0] = f2bf(fmaxf(bf2f(vals[0]) + p0.x, 0.f));
        o[1] = f2bf(fmaxf(bf2f(vals[1]) + p0.y, 0.f));
        o[2] = f2bf(fmaxf(bf2f(vals[2]) + p0.z, 0.f));
        o[3] = f2bf(fmaxf(bf2f(vals[3]) + p0.w, 0.f));
        o[4] = f2bf(fmaxf(bf2f(vals[4]) + p1.x, 0.f));
        o[5] = f2bf(fmaxf(bf2f(vals[5]) + p1.y, 0.f));
        o[6] = f2bf(fmaxf(bf2f(vals[6]) + p1.z, 0.f));
        o[7] = f2bf(fmaxf(bf2f(vals[7]) + p1.w, 0.f));
        *(u16x8*)(ok + dst) = o;
      } else if (part == 0){
        *(u16x8*)(oq + dst) = vals;
      } else {
        *(u16x8*)(ov + dst) = vals;
      }
    }
  }
}

// ------ gemm_proj: 256x256, counted-vmcnt dbuf pipeline (r10 winner) ------
__global__ __launch_bounds__(512, 1) void gemm_proj(
    const unsigned short* __restrict__ A,
    const unsigned short* __restrict__ Bt,
    const float* __restrict__ bias,
    float* __restrict__ op,
    int NTN)
{
  __shared__ unsigned short As[2][256 * 64];
  __shared__ unsigned short Bs[2][256 * 64];
  int tid = threadIdx.x, lane = tid & 63, wid = tid >> 6;
  int nwg = gridDim.x;
  int b0 = blockIdx.x;
  int cpx = nwg >> 3;
  int swz = (b0 & 7) * cpx + (b0 >> 3);
  int tm = swz / NTN, tn = swz - tm * NTN;
  int row0 = tm << 8, col0 = tn << 8;
  int wrow = wid >> 2, wcol = wid & 3;       // wave owns 128x64 of C

  f32x4 acc[8][4];
  #pragma unroll
  for (int m = 0; m < 8; ++m)
    #pragma unroll
    for (int n = 0; n < 4; ++n)
      acc[m][n] = (f32x4){0.f, 0.f, 0.f, 0.f};

  auto STAGE = [&](int buf, int kt){
    int k0 = kt * 64;
    #pragma unroll
    for (int it = 0; it < 4; ++it){
      int c = it * 512 + tid;
      int r = c >> 3;
      int scs = ((c & 7) ^ (r & 7)) * 8;
      gload_lds16(A + (size_t)(row0 + r) * 512 + k0 + scs, &As[buf][c * 8]);
    }
    #pragma unroll
    for (int it = 0; it < 4; ++it){
      int c = it * 512 + tid;
      int r = c >> 3;
      int scs = ((c & 7) ^ (r & 7)) * 8;
      gload_lds16(Bt + (size_t)(col0 + r) * 512 + k0 + scs, &Bs[buf][c * 8]);
    }
  };
  auto COMPUTE = [&](int buf){
    bf16x8 bfr[4][2];
    #pragma unroll
    for (int kk = 0; kk < 2; ++kk){
      int kcs = ((kk * 4 + (lane >> 4)) ^ (lane & 7)) * 8;
      #pragma unroll
      for (int n = 0; n < 4; ++n)
        bfr[n][kk] = *(const bf16x8*)&Bs[buf][(wcol * 64 + n * 16 + (lane & 15)) * 64 + kcs];
    }
    __builtin_amdgcn_s_setprio(1);
    #pragma unroll
    for (int kk = 0; kk < 2; ++kk){
      int kcs = ((kk * 4 + (lane >> 4)) ^ (lane & 7)) * 8;
      #pragma unroll
      for (int m = 0; m < 8; ++m){
        bf16x8 af = *(const bf16x8*)&As[buf][(wrow * 128 + m * 16 + (lane & 15)) * 64 + kcs];
        #pragma unroll
        for (int n = 0; n < 4; ++n)
          acc[m][n] = __builtin_amdgcn_mfma_f32_16x16x32_bf16(af, bfr[n][kk], acc[m][n], 0, 0, 0);
      }
    }
    __builtin_amdgcn_s_setprio(0);
  };

  STAGE(0, 0);
  STAGE(1, 1);
  #pragma unroll
  for (int t = 0; t < 8; ++t){
    if (t < 7) asm volatile("s_waitcnt vmcnt(8)" ::: "memory");
    else       asm volatile("s_waitcnt vmcnt(0)" ::: "memory");
    __builtin_amdgcn_s_barrier();
    __builtin_amdgcn_sched_barrier(0);
    COMPUTE(t & 1);
    asm volatile("" ::: "memory");
    __builtin_amdgcn_s_barrier();
    if (t + 2 < 8) STAGE(t & 1, t + 2);
  }

  #pragma unroll
  for (int m = 0; m < 8; ++m){
    #pragma unroll
    for (int n = 0; n < 4; ++n){
      #pragma unroll
      for (int r = 0; r < 4; ++r){
        int rrow = row0 + wrow * 128 + m * 16 + (lane >> 4) * 4 + r;
        int ccol = col0 + wcol * 64 + n * 16 + (lane & 15);
        op[(size_t)rrow * 512 + ccol] = acc[m][n][r] + bias[ccol];
      }
    }
  }
}

// ---- kv = k^T v via MFMA + ksum via ones-fragment + pair-planar v_p ------
__global__ __launch_bounds__(256) void kv_k(const unsigned short* __restrict__ kbuf,
                                            const unsigned short* __restrict__ vbuf,
                                            float* __restrict__ kvb,
                                            float* __restrict__ ksb,
                                            uint32_t* __restrict__ vp){
  int bh  = blockIdx.x >> 2;
  int seg = blockIdx.x & 3;
  __shared__ unsigned short ksT[32 * 64];
  __shared__ unsigned short vsT[32 * 64];
  __shared__ float red[4][1024];
  __shared__ float red2[4][32];
  int tid = threadIdx.x, lane = tid & 63, w = tid >> 6;
  const unsigned short* kb = kbuf + (size_t)bh * 131072 + (size_t)seg * 32768;
  const unsigned short* vb = vbuf + (size_t)bh * 131072 + (size_t)seg * 32768;
  uint32_t* vpb = vp + (size_t)bh * 65536 + seg * 1024;

  f32x4 acc00 = (f32x4){0,0,0,0}, acc01 = (f32x4){0,0,0,0};
  f32x4 acc10 = (f32x4){0,0,0,0}, acc11 = (f32x4){0,0,0,0};
  f32x4 ksa0  = (f32x4){0,0,0,0}, ksa1  = (f32x4){0,0,0,0};
  bf16x8 ones;
  #pragma unroll
  for (int j = 0; j < 8; ++j) ones[j] = (short)0x3F80;   // bf16 1.0

  int tok = tid >> 2;        // 0..63
  int ec  = (tid & 3) * 8;   // channel base 0,8,16,24

  for (int t = 0; t < 16; ++t){
    __syncthreads();         // prior tile's reads complete
    u16x8 kk8 = *(const u16x8*)(kb + ((size_t)t * 64 + tok) * 32 + ec);
    u16x8 vv8 = *(const u16x8*)(vb + ((size_t)t * 64 + tok) * 32 + ec);
    #pragma unroll
    for (int j = 0; j < 8; ++j){
      int row = ec + j;
      int sw = (row + (row >> 3)) & 7;
      int col = ((((tok >> 3) ^ sw) << 3) | (tok & 7));
      ksT[row * 64 + col] = kk8[j];
      vsT[row * 64 + col] = vv8[j];
    }
    __syncthreads();         // tile ready
    #pragma unroll
    for (int i = 0; i < 4; ++i){
      int idx = i * 256 + tid;
      int pr = idx >> 6, tk = idx & 63;
      int r0 = pr * 2, r1 = r0 + 1;
      int sw0 = (r0 + (r0 >> 3)) & 7;
      int sw1 = (r1 + (r1 >> 3)) & 7;
      uint32_t lo = vsT[r0 * 64 + ((((tk >> 3) ^ sw0) << 3) | (tk & 7))];
      uint32_t hi = vsT[r1 * 64 + ((((tk >> 3) ^ sw1) << 3) | (tk & 7))];
      vpb[pr * 4096 + t * 64 + tk] = lo | (hi << 16);
    }
    if ((t & 3) == w){       // this wave owns this K-slice
      #pragma unroll
      for (int kk = 0; kk < 2; ++kk){
        int kc = kk * 4 + (lane >> 4);       // 16B chunk of k-offset
        int r0 = lane & 15, r1 = 16 + (lane & 15);
        int sw0 = (r0 + (r0 >> 3)) & 7;
        int sw1 = (r1 + (r1 >> 3)) & 7;
        bf16x8 a0 = *(const bf16x8*)&ksT[r0 * 64 + ((kc ^ sw0) << 3)];
        bf16x8 a1 = *(const bf16x8*)&ksT[r1 * 64 + ((kc ^ sw1) << 3)];
        bf16x8 b0 = *(const bf16x8*)&vsT[r0 * 64 + ((kc ^ sw0) << 3)];
        bf16x8 b1 = *(const bf16x8*)&vsT[r1 * 64 + ((kc ^ sw1) << 3)];
        acc00 = __builtin_amdgcn_mfma_f32_16x16x32_bf16(a0, b0, acc00, 0, 0, 0);
        acc01 = __builtin_amdgcn_mfma_f32_16x16x32_bf16(a0, b1, acc01, 0, 0, 0);
        acc10 = __builtin_amdgcn_mfma_f32_16x16x32_bf16(a1, b0, acc10, 0, 0, 0);
        acc11 = __builtin_amdgcn_mfma_f32_16x16x32_bf16(a1, b1, acc11, 0, 0, 0);
        ksa0  = __builtin_amdgcn_mfma_f32_16x16x32_bf16(a0, ones, ksa0, 0, 0, 0);
        ksa1  = __builtin_amdgcn_mfma_f32_16x16x32_bf16(a1, ones, ksa1, 0, 0, 0);
      }
    }
  }
  __syncthreads();
  {
    int q = lane >> 4, c16 = lane & 15;
    #pragma unroll
    for (int r = 0; r < 4; ++r){
      red[w][(q * 4 + r) * 32 + c16]           = acc00[r];
      red[w][(q * 4 + r) * 32 + 16 + c16]      = acc01[r];
      red[w][(16 + q * 4 + r) * 32 + c16]      = acc10[r];
      red[w][(16 + q * 4 + r) * 32 + 16 + c16] = acc11[r];
    }
    if (c16 == 0){
      #pragma unroll
      for (int r = 0; r < 4; ++r){
        red2[w][q * 4 + r]      = ksa0[r];
        red2[w][16 + q * 4 + r] = ksa1[r];
      }
    }
  }
  __syncthreads();
  for (int s = tid; s < 1024; s += 256){
    float sum = red[0][s] + red[1][s] + red[2][s] + red[3][s];
    atomicAdd(&kvb[bh * 1024 + s], sum);
  }
  if (tid < 32){
    atomicAdd(&ksb[bh * 32 + tid],
              red2[0][tid] + red2[1][tid] + red2[2][tid] + red2[3][tid]);
  }
}

// ------- out = z*(q@kv) + depthwise5x5(v_p) + bias, 8-band split ----------
// 2048 blocks; XCD-affinity map: each XCD owns 32 whole bh (vp/q L2 reuse).
__global__ __launch_bounds__(256, 4) void attn_k3(
    const unsigned short* __restrict__ qbuf,
    const uint32_t* __restrict__ vp,
    const float* __restrict__ kvb,
    const float* __restrict__ ksb,
    const float* __restrict__ dwc_w,
    const float* __restrict__ dwc_b,
    unsigned short* __restrict__ attn)
{
  int b0 = blockIdx.x;
  int xcd = b0 & 7, slot = b0 >> 3;
  int bh   = xcd * 32 + (slot >> 3);   // 0..255
  int band = slot & 7;                 // 0..7, 512 tokens (8 fm rows)
  int tid = threadIdx.x, lane = tid & 63, w = tid >> 6;
  __shared__ uint32_t outs32[512][18];
  unsigned short* outs = (unsigned short*)outs32;
  __shared__ float zs[512];
  __shared__ float ksum_s[32];

  const unsigned short* qb = qbuf + (size_t)bh * 4096 * 32 + (size_t)band * 512 * 32;
  const uint32_t* vpb = vp + (size_t)bh * 65536;

  if (tid < 32) ksum_s[tid] = ksb[bh * 32 + tid];
  __syncthreads();

  for (int p = 0; p < 2; ++p){
    int t = p * 256 + tid;
    float zd = 0.f;
    #pragma unroll
    for (int pp = 0; pp < 4; ++pp){
      u16x8 qq = *(const u16x8*)(qb + (size_t)t * 32 + pp * 8);
      #pragma unroll
      for (int i = 0; i < 8; ++i) zd += bf2f(qq[i]) * ksum_s[pp * 8 + i];
    }
    zs[t] = 1.f / (zd + 1e-6f);
  }

  bf16x8 bfr[2];
  #pragma unroll
  for (int nc = 0; nc < 2; ++nc){
    bf16x8 t8;
    #pragma unroll
    for (int j = 0; j < 8; ++j){
      int c = (lane >> 4) * 8 + j;
      int d = nc * 16 + (lane & 15);
      t8[j] = (short)f2bf(kvb[bh * 1024 + c * 32 + d]);
    }
    bfr[nc] = t8;
  }
  __syncthreads();

  for (int p = 0; p < 2; ++p){
    f32x4 acc[4][2];
    #pragma unroll
    for (int m = 0; m < 4; ++m){ acc[m][0] = (f32x4){0.f,0.f,0.f,0.f}; acc[m][1] = (f32x4){0.f,0.f,0.f,0.f}; }
    #pragma unroll
    for (int m = 0; m < 4; ++m){
      int row = p * 256 + w * 64 + m * 16 + (lane & 15);
      bf16x8 af = *(const bf16x8*)(qb + (size_t)row * 32 + (lane >> 4) * 8);
      acc[m][0] = __builtin_amdgcn_mfma_f32_16x16x32_bf16(af, bfr[0], acc[m][0], 0, 0, 0);
      acc[m][1] = __builtin_amdgcn_mfma_f32_16x16x32_bf16(af, bfr[1], acc[m][1], 0, 0, 0);
    }
    #pragma unroll
    for (int m = 0; m < 4; ++m)
      #pragma unroll
      for (int nc = 0; nc < 2; ++nc)
        #pragma unroll
        for (int r = 0; r < 4; ++r){
          int lrow = p * 256 + w * 64 + m * 16 + (lane >> 4) * 4 + r;
          int col = nc * 16 + (lane & 15);
          outs[lrow * 36 + col] = f2bf(acc[m][nc][r] * zs[lrow]);
        }
  }
  __syncthreads();

  int x = lane;
  int y0 = band * 8;
  int xm2 = lane - 2, xm1 = lane - 1, xp1 = lane + 1, xp2 = lane + 2;

  for (int pair = 0; pair < 4; ++pair){
    int dbase = w * 8 + pair * 2;
    int pr = w * 4 + pair;
    float w0[25], w1[25];
    #pragma unroll
    for (int j = 0; j < 25; ++j){
      w0[j] = dwc_w[dbase * 25 + j];
      w1[j] = dwc_w[(dbase + 1) * 25 + j];
    }
    float cb0 = dwc_b[dbase], cb1 = dwc_b[dbase + 1];

    uint32_t rowd[12];
    #pragma unroll
    for (int il = 0; il < 12; ++il){
      int yi = y0 - 2 + il;
      rowd[il] = (yi >= 0 && yi < 64)
        ? vpb[pr * 4096 + yi * 64 + x] : 0u;
    }

    float a0[5], a1[5];
    #pragma unroll
    for (int il = 0; il < 12; ++il){
      uint32_t d0 = rowd[il];
      uint32_t dm2 = (uint32_t)__shfl((int)d0, xm2); if (lane < 2)  dm2 = 0;
      uint32_t dm1 = (uint32_t)__shfl((int)d0, xm1); if (lane < 1)  dm1 = 0;
      uint32_t dp1 = (uint32_t)__shfl((int)d0, xp1); if (lane > 62) dp1 = 0;
      uint32_t dp2 = (uint32_t)__shfl((int)d0, xp2); if (lane > 61) dp2 = 0;
      float f0[5], f1[5];
      f0[0] = bflo(dm2); f1[0] = bfhi(dm2);
      f0[1] = bflo(dm1); f1[1] = bfhi(dm1);
      f0[2] = bflo(d0);  f1[2] = bfhi(d0);
      f0[3] = bflo(dp1); f1[3] = bfhi(dp1);
      f0[4] = bflo(dp2); f1[4] = bfhi(dp2);
      #pragma unroll
      for (int ky = 0; ky < 5; ++ky){
        int ol = il - ky;
        if (ol < 0 || ol > 7) continue;
        int s = ol % 5;
        if (ky == 0){
          a0[s] = w0[0] * f0[0];
          a1[s] = w1[0] * f1[0];
          #pragma unroll
          for (int kx = 1; kx < 5; ++kx){
            a0[s] += w0[kx] * f0[kx];
            a1[s] += w1[kx] * f1[kx];
          }
        } else {
          #pragma unroll
          for (int kx = 0; kx < 5; ++kx){
            a0[s] += w0[ky * 5 + kx] * f0[kx];
            a1[s] += w1[ky * 5 + kx] * f1[kx];
          }
        }
      }
      if (il >= 4){
        int ol = il - 4;
        int s = ol % 5;
        int ltok = ol * 64 + x;
        uint32_t ov = outs32[ltok][pr];
        float o0 = bflo(ov) + a0[s] + cb0;
        float o1 = bfhi(ov) + a1[s] + cb1;
        outs32[ltok][pr] = ((uint32_t)f2bf(o1) << 16) | (uint32_t)f2bf(o0);
      }
    }
  }
  __syncthreads();

  int b = bh >> 4, h = bh & 15;
  size_t gbase = ((size_t)b * 4096 + (size_t)band * 512) * 512 + h * 32;
  #pragma unroll
  for (int it = 0; it < 16; ++it){
    int idx = it * 256 + tid;
    int token = idx >> 3, sub = idx & 7;
    uint2 vv = *(const uint2*)&outs32[token][sub * 2];
    *(uint2*)(attn + gbase + (size_t)token * 512 + sub * 4) = vv;
  }
}

extern "C" void kernel_launch(void* const* d_in, const int* in_sizes, int n_in,
                              void* d_out, int out_size, void* d_ws, size_t ws_size,
                              hipStream_t stream) {
  const float* x       = (const float*)d_in[0];
  const float* Wqkv    = (const float*)d_in[1];
  const float* bqkv    = (const float*)d_in[2];
  const float* pos_enc = (const float*)d_in[3];
  const float* dwc_w   = (const float*)d_in[4];
  const float* dwc_b   = (const float*)d_in[5];
  const float* Wproj   = (const float*)d_in[6];
  const float* bproj   = (const float*)d_in[7];
  float* out = (float*)d_out;
  char* ws = (char*)d_ws;

  const size_t off_xb    = 0;                 // xb; reused as v_p after gemm_qkv
  const size_t off_wqkvt = 67108864;
  const size_t off_wprojt= 68681728;
  const size_t off_q     = 69206016;
  const size_t off_k     = 136314880;
  const size_t off_v     = 203423744;
  const size_t off_kv    = 270532608;
  const size_t off_ksum  = 271581184;
  const size_t needed    = 271613952;
  if (ws_size < needed) return;

  unsigned short* xb     = (unsigned short*)(ws + off_xb);
  unsigned short* wqkvt  = (unsigned short*)(ws + off_wqkvt);
  unsigned short* wprojt = (unsigned short*)(ws + off_wprojt);
  unsigned short* qb     = (unsigned short*)(ws + off_q);
  unsigned short* kb     = (unsigned short*)(ws + off_k);
  unsigned short* vb     = (unsigned short*)(ws + off_v);
  float* kvb = (float*)(ws + off_kv);
  float* ksb = (float*)(ws + off_ksum);
  unsigned short* attn = kb;                  // k dead after kv_k
  uint32_t* vp = (uint32_t*)(ws + off_xb);    // xb dead after gemm_qkv

  convert_x_k<<<16384, 256, 0, stream>>>(x, xb);
  transpose_w_k<<<256, 256, 0, stream>>>(Wqkv, Wproj, wqkvt, wprojt);
  gemm_qkv<<<3072, 512, 0, stream>>>(xb, wqkvt, bqkv, pos_enc, qb, kb, vb, 12);
  (void)hipMemsetAsync(kvb, 0, (size_t)(256 * 1024 + 256 * 32) * sizeof(float), stream);
  kv_k<<<1024, 256, 0, stream>>>(kb, vb, kvb, ksb, vp);
  attn_k3<<<2048, 256, 0, stream>>>(qb, vp, kvb, ksb, dwc_w, dwc_b, attn);
  gemm_proj<<<512, 512, 0, stream>>>(attn, wprojt, bproj, out, 2);
}